// Round 6
// baseline (58.302 us; speedup 1.0000x reference)
//
#include <hip/hip_runtime.h>
#include <hip/hip_bf16.h>

namespace {

using frag_t    = __attribute__((ext_vector_type(8))) short;   // 8 bf16 = 16 B
using f32x4     = __attribute__((ext_vector_type(4))) float;   // MFMA acc
using float4_t  = __attribute__((ext_vector_type(4))) float;

constexpr int BATCH = 32;
constexpr int CIN   = 64;
constexpr int HWD   = 56;
constexpr int KOUT  = 128;
constexpr int SP    = HWD * HWD;        // 3136
constexpr int KD    = 9 * CIN;          // 576
constexpr int BN    = 128;              // spatial tile
constexpr int HALO  = 57;
constexpr int NST   = 256;              // staged rows: 4 subtiles x 64 (valid reads <= 241)
constexpr int NTILES= SP / BN + 1;      // 25
constexpr int NWG   = NTILES * BATCH;   // 800 = 8 XCD x 100 (bijective swizzle)
constexpr int WB    = (KOUT * KD + 255) / 256;

__device__ inline unsigned short f2bf(float f) {
    __hip_bfloat16 h = __float2bfloat16(f);
    return __builtin_bit_cast(unsigned short, h);
}

// ---- weight repack: w[k][c][ky][kx] f32 -> wpA[kc][kout][32] bf16 (kk = t*64+c) ----
__global__ __launch_bounds__(256)
void wconv_kernel(const float* __restrict__ w, unsigned short* __restrict__ wpA)
{
    const int idx = blockIdx.x * 256 + threadIdx.x;
    if (idx < KOUT * KD) {
        const int kout = idx / KD, kk = idx - kout * KD;
        const int kc = kk >> 5, e = kk & 31;
        const int t = kk >> 6, c = kk & 63;
        const int ky = t / 3, kx = t - ky * 3;
        wpA[(kc * KOUT + kout) * 32 + e] = f2bf(w[((kout * CIN + c) * 3 + ky) * 3 + kx]);
    }
}

// ---- fused conv: in-block NCHW->transposed-bf16 staging + implicit-GEMM MFMA ----
__global__ __launch_bounds__(256, 3)
void conv_fused(const float* __restrict__ x, const unsigned short* __restrict__ wpA,
                const float* __restrict__ off, float* __restrict__ out)
{
    // xs[row][c] bf16, ushort idx = r*64 + (c ^ ((r&7)<<3))
    __shared__ unsigned short xs[NST * 64];
    __shared__ float ls[64][65];               // f32 transpose bounce, 65-pad (2-way = free)

    const int d    = blockIdx.x;
    const int wk   = (d & 7) * (NWG / 8) + (d >> 3);   // XCD swizzle: 4 images/XCD
    const int b    = wk / NTILES;
    const int sp0  = (wk - b * NTILES) * BN;
    const int tid  = threadIdx.x;
    const int lane = tid & 63;
    const int wid  = tid >> 6;

    // ---------- stage window: 4 subtiles of 64 rows, two-stage LDS transpose ----------
    {
        const float* xb  = x + (size_t)b * CIN * SP;
        const int    spo = (tid & 15) * 4;
        const int    cb  = tid >> 4;           // 0..15
        for (int s4 = 0; s4 < 4; ++s4) {
            const int g0 = sp0 - HALO + s4 * 64 + spo;
            #pragma unroll
            for (int j = 0; j < 4; ++j) {
                const int c = cb + 16 * j;
                const float* xc = xb + (size_t)c * SP;
                float4_t v;
                if (g0 >= 0 && g0 + 3 < SP) {
                    v = *(const float4_t*)&xc[g0];
                } else {                       // edge straddle: per-element clamp
                    #pragma unroll
                    for (int k2 = 0; k2 < 4; ++k2) {
                        int g = g0 + k2; g = min(max(g, 0), SP - 1);
                        v[k2] = xc[g];
                    }
                }
                ls[spo + 0][c] = v.x; ls[spo + 1][c] = v.y;
                ls[spo + 2][c] = v.z; ls[spo + 3][c] = v.w;
            }
            __syncthreads();
            #pragma unroll
            for (int j = 0; j < 2; ++j) {
                const int t2 = tid + 256 * j;  // 512 slots = 64 sp x 8 e
                const int sp = t2 >> 3, e = t2 & 7;
                frag_t u;
                #pragma unroll
                for (int q = 0; q < 8; ++q)
                    u[q] = (short)f2bf(ls[sp][e * 8 + q]);
                const int spg = s4 * 64 + sp;
                *(frag_t*)&xs[spg * 64 + ((e * 8) ^ ((spg & 7) << 3))] = u;
            }
            __syncthreads();                   // protect ls before next subtile
        }
    }

    const int wm  = (wid >> 1) * 64;   // kout offset of this wave
    const int wn  = (wid & 1) * 64;    // spatial offset of this wave
    const int l15 = lane & 15;
    const int l4  = lane >> 4;

    // ---------- per-(tap, nf) validity masks ----------
    unsigned long long mbits = 0ull;
    int yv[4], xv[4];
    #pragma unroll
    for (int nf = 0; nf < 4; ++nf) {
        const int sp = sp0 + wn + nf * 16 + l15;
        yv[nf] = sp / HWD;
        xv[nf] = sp - yv[nf] * HWD;
    }
    #pragma unroll
    for (int t = 0; t < 9; ++t) {
        const int dy = t / 3 - 1, dx = t % 3 - 1;
        #pragma unroll
        for (int nf = 0; nf < 4; ++nf) {
            const bool v = ((unsigned)(yv[nf] + dy) < (unsigned)HWD) &
                           ((unsigned)(xv[nf] + dx) < (unsigned)HWD);
            mbits |= (unsigned long long)(v ? 1 : 0) << (t * 4 + nf);
        }
    }

    const unsigned short* abase = wpA + (size_t)(wm + l15) * 32 + 8 * l4;
    const int cread = 8 * l4;
    const frag_t zf = {0,0,0,0,0,0,0,0};

    f32x4 acc[4][4] = {};              // [mi][nf]

    // ---------- K loop: 18 chunks, no barriers ----------
    #pragma unroll
    for (int kc = 0; kc < 18; ++kc) {
        const int t  = kc >> 1;
        const int c0 = (kc & 1) * 32;
        const int s    = (t / 3 - 1) * HWD + (t % 3 - 1);
        const int row0 = wn + l15 + HALO + s;          // in [0, 241]
        const int sw   = (row0 & 7) << 3;
        frag_t a[4], bfr[4];
        #pragma unroll
        for (int mi = 0; mi < 4; ++mi)
            a[mi] = *(const frag_t*)(abase + (size_t)(kc * KOUT + mi * 16) * 32);
        #pragma unroll
        for (int nf = 0; nf < 4; ++nf) {
            const frag_t bl = *(const frag_t*)&xs[(row0 + 16 * nf) * 64
                                                 + ((c0 + cread) ^ sw)];
            bfr[nf] = ((mbits >> (t * 4 + nf)) & 1) ? bl : zf;
        }
        #pragma unroll
        for (int mi = 0; mi < 4; ++mi)
            #pragma unroll
            for (int nf = 0; nf < 4; ++nf)
                acc[mi][nf] = __builtin_amdgcn_mfma_f32_16x16x32_bf16(
                    a[mi], bfr[nf], acc[mi][nf], 0, 0, 0);
    }

    // ---------- epilogue ----------
    const int spn = sp0 + wn + l15;
    #pragma unroll
    for (int mi = 0; mi < 4; ++mi) {
        const int km = wm + 16 * mi + 4 * l4;
        #pragma unroll
        for (int reg = 0; reg < 4; ++reg) {
            const int  kk  = km + reg;
            const float ofv = off[kk];
            float* ob = out + (size_t)(b * KOUT + kk) * SP;
            #pragma unroll
            for (int nf = 0; nf < 4; ++nf) {
                const int sp = spn + 16 * nf;
                if (sp < SP) ob[sp] = acc[mi][nf][reg] + ofv;
            }
        }
    }
}

// ---- fallback: round-1 fp32 direct conv ----
__global__ __launch_bounds__(256)
void conv3x3_kernel(const float* __restrict__ x, const float* __restrict__ w,
                    const float* __restrict__ off, float* __restrict__ out)
{
    const int s  = blockIdx.x * 256 + threadIdx.x;
    const int b  = s / SP;
    const int sp = s - b * SP;
    const int y  = sp / HWD;
    const int xx = sp - y * HWD;
    const int k0 = blockIdx.y * 4;

    const int   xm1 = (xx > 0) ? xx - 1 : 0;
    const int   xp1 = (xx < HWD - 1) ? xx + 1 : HWD - 1;
    const float m0  = (xx > 0) ? 1.f : 0.f;
    const float m2  = (xx < HWD - 1) ? 1.f : 0.f;

    int ro[3]; float msk[3][3];
    #pragma unroll
    for (int ky = 0; ky < 3; ++ky) {
        const int  yy = y + ky - 1;
        const bool ok = (unsigned)yy < (unsigned)HWD;
        const float rm = ok ? 1.f : 0.f;
        ro[ky] = (ok ? yy : 0) * HWD;
        msk[ky][0] = rm * m0; msk[ky][1] = rm; msk[ky][2] = rm * m2;
    }
    float acc[4] = {0.f, 0.f, 0.f, 0.f};
    const float* xb = x + (size_t)b * CIN * SP;
    for (int c = 0; c < CIN; ++c) {
        const float* xc = xb + (size_t)c * SP;
        #pragma unroll
        for (int ky = 0; ky < 3; ++ky) {
            const float* xr = xc + ro[ky];
            const float v0 = xr[xm1] * msk[ky][0];
            const float v1 = xr[xx]  * msk[ky][1];
            const float v2 = xr[xp1] * msk[ky][2];
            const int wi = c * 9 + ky * 3;
            #pragma unroll
            for (int kk = 0; kk < 4; ++kk) {
                const float* wr = w + (size_t)(k0 + kk) * (CIN * 9) + wi;
                acc[kk] = fmaf(v0, wr[0], acc[kk]);
                acc[kk] = fmaf(v1, wr[1], acc[kk]);
                acc[kk] = fmaf(v2, wr[2], acc[kk]);
            }
        }
    }
    #pragma unroll
    for (int kk = 0; kk < 4; ++kk)
        out[(size_t)(b * KOUT + k0 + kk) * SP + sp] = acc[kk] + off[k0 + kk];
}

} // namespace

extern "C" void kernel_launch(void* const* d_in, const int* in_sizes, int n_in,
                              void* d_out, int out_size, void* d_ws, size_t ws_size,
                              hipStream_t stream)
{
    const float* x   = (const float*)d_in[0];
    const float* w   = (const float*)d_in[1];
    const float* off = (const float*)d_in[2];
    float* out = (float*)d_out;

    const size_t wpa_bytes = (size_t)KOUT * KD * 2;          // 147456

    if (ws_size >= wpa_bytes) {
        unsigned short* wpA = (unsigned short*)d_ws;
        wconv_kernel<<<WB, 256, 0, stream>>>(w, wpA);
        conv_fused<<<NWG, dim3(256, 1, 1), 0, stream>>>(x, wpA, off, out);
    } else {
        dim3 grid((BATCH * SP) / 256, KOUT / 4);
        conv3x3_kernel<<<grid, dim3(256, 1, 1), 0, stream>>>(x, w, off, out);
    }
}

// Round 7
// 52.290 us; speedup vs baseline: 1.1150x; 1.1150x over previous
//
#include <hip/hip_runtime.h>
#include <hip/hip_bf16.h>

namespace {

using frag_t    = __attribute__((ext_vector_type(8))) short;   // 8 bf16 = 16 B
using f32x4     = __attribute__((ext_vector_type(4))) float;   // MFMA acc
using float4_t  = __attribute__((ext_vector_type(4))) float;

constexpr int BATCH = 32;
constexpr int CIN   = 64;
constexpr int HWD   = 56;
constexpr int KOUT  = 128;
constexpr int SP    = HWD * HWD;        // 3136
constexpr int KD    = 9 * CIN;          // 576
constexpr int BN    = 128;              // spatial tile
constexpr int HALO  = 57;
constexpr int NEXT  = BN + 2 * HALO;    // 242 staged rows
constexpr int NTILES= SP / BN + 1;      // 25
constexpr int NTT   = NTILES * BATCH;   // 800 tiles
constexpr int NBLK  = 512;              // persistent blocks = 2/CU, all resident
constexpr int TT    = BATCH * (SP / 64);
constexpr int WB    = (KOUT * KD + 255) / 256;

__device__ inline unsigned short f2bf(float f) {
    __hip_bfloat16 h = __float2bfloat16(f);
    return __builtin_bit_cast(unsigned short, h);
}

// ---- prep: (a) transpose x -> xT[b][sp][c] bf16; (b) repack w -> wpA[kc][kout][32] ----
__global__ __launch_bounds__(256)
void prep_kernel(const float* __restrict__ x, const float* __restrict__ w,
                 unsigned short* __restrict__ wpA, unsigned short* __restrict__ xT)
{
    if (blockIdx.x >= TT) {
        const int idx = (blockIdx.x - TT) * 256 + threadIdx.x;
        if (idx < KOUT * KD) {
            const int kout = idx / KD, kk = idx - kout * KD;
            const int kc = kk >> 5, e = kk & 31;
            const int t = kk >> 6, c = kk & 63;
            const int ky = t / 3, kx = t - ky * 3;
            wpA[(kc * KOUT + kout) * 32 + e] = f2bf(w[((kout * CIN + c) * 3 + ky) * 3 + kx]);
        }
        return;
    }
    __shared__ float ls[64][68];
    const int bb   = blockIdx.x / (SP / 64);
    const int tile = blockIdx.x - bb * (SP / 64);
    const int sp0  = tile * 64;
    const int tid  = threadIdx.x;
    const int cq   = tid >> 4;
    const int spo  = (tid & 15) * 4;
    const float* xb = x + (size_t)bb * CIN * SP;
    #pragma unroll
    for (int j = 0; j < 4; ++j) {
        const int c = cq + 16 * j;
        float4_t v = *(const float4_t*)&xb[(size_t)c * SP + sp0 + spo];
        ls[spo + 0][c] = v.x; ls[spo + 1][c] = v.y;
        ls[spo + 2][c] = v.z; ls[spo + 3][c] = v.w;
    }
    __syncthreads();
    unsigned short* xo = xT + (size_t)(bb * SP + sp0) * 64;
    #pragma unroll
    for (int j = 0; j < 2; ++j) {
        const int s  = tid + 256 * j;
        const int sp = s >> 3, e = s & 7;
        frag_t u;
        #pragma unroll
        for (int q = 0; q < 8; ++q)
            u[q] = (short)f2bf(ls[sp][e * 8 + q]);
        *(frag_t*)&xo[sp * 64 + e * 8] = u;
    }
}

// ---- persistent, tile-pipelined implicit-GEMM conv ----
__global__ __launch_bounds__(256, 2)
void conv_pipe(const unsigned short* __restrict__ xT, const unsigned short* __restrict__ wpA,
               const float* __restrict__ off, float* __restrict__ out)
{
    // xs[buf][row][c] bf16; slot [r][z] holds xT[g(r)][z ^ ((r&7)<<3)]
    __shared__ unsigned short xs[2][NEXT * 64];   // 2 x 31 KB

    const int bid  = blockIdx.x;
    const int wk0  = (bid & 7) * (NBLK / 8) + (bid >> 3);  // XCD-chunked, bijective on 512
    const int tid  = threadIdx.x;
    const int lane = tid & 63;
    const int wid  = tid >> 6;
    const int lsw  = ((lane & 7) * 8) ^ ((lane >> 3) << 3);

    const int wm   = (wid >> 1) * 64;   // kout offset
    const int wn   = (wid & 1) * 64;    // spatial offset
    const int l15  = lane & 15;
    const int l4   = lane >> 4;
    const unsigned short* abase = wpA + (size_t)(wm + l15) * 32 + 8 * l4;
    const int cread = 8 * l4;

    // issue 242-row window stage for `tile` into xs[buf] (no wait)
    auto stage = [&](int buf, int tile) {
        const int b   = tile / NTILES;
        const int sp0 = (tile - b * NTILES) * BN;
        const unsigned short* xb = xT + (size_t)b * SP * 64;
        #pragma unroll
        for (int it = 0; it < 8; ++it) {
            const int R0 = it * 32 + wid * 8;       // wave-uniform base row
            const int r  = R0 + (lane >> 3);
            if (r < NEXT) {
                int g = sp0 - HALO + r;
                g = min(max(g, 0), SP - 1);
                __builtin_amdgcn_global_load_lds(
                    (const __attribute__((address_space(1))) unsigned int*)
                        (xb + (size_t)g * 64 + lsw),
                    (__attribute__((address_space(3))) unsigned int*)
                        &xs[buf][R0 * 64 + lane * 8],
                    16, 0, 0);
            }
        }
    };

    auto compute = [&](int buf, int tile) {
        const int b   = tile / NTILES;
        const int sp0 = (tile - b * NTILES) * BN;

        // per-(tap, nf) validity masks
        unsigned long long mbits = 0ull;
        int yv[4], xv[4];
        #pragma unroll
        for (int nf = 0; nf < 4; ++nf) {
            const int sp = sp0 + wn + nf * 16 + l15;
            yv[nf] = sp / HWD;
            xv[nf] = sp - yv[nf] * HWD;
        }
        #pragma unroll
        for (int t = 0; t < 9; ++t) {
            const int dy = t / 3 - 1, dx = t % 3 - 1;
            #pragma unroll
            for (int nf = 0; nf < 4; ++nf) {
                const bool v = ((unsigned)(yv[nf] + dy) < (unsigned)HWD) &
                               ((unsigned)(xv[nf] + dx) < (unsigned)HWD);
                mbits |= (unsigned long long)(v ? 1 : 0) << (t * 4 + nf);
            }
        }

        const frag_t zf = {0,0,0,0,0,0,0,0};
        f32x4 acc[4][4] = {};
        const unsigned short* xsb = &xs[buf][0];

        #pragma unroll
        for (int kc = 0; kc < 18; ++kc) {
            const int t  = kc >> 1;
            const int c0 = (kc & 1) * 32;
            const int s    = (t / 3 - 1) * HWD + (t % 3 - 1);
            const int row0 = wn + l15 + HALO + s;          // in [0, 241]
            const int sw   = (row0 & 7) << 3;
            frag_t a[4], bfr[4];
            #pragma unroll
            for (int mi = 0; mi < 4; ++mi)
                a[mi] = *(const frag_t*)(abase + (size_t)(kc * KOUT + mi * 16) * 32);
            #pragma unroll
            for (int nf = 0; nf < 4; ++nf) {
                const frag_t bl = *(const frag_t*)&xsb[(row0 + 16 * nf) * 64
                                                      + ((c0 + cread) ^ sw)];
                bfr[nf] = ((mbits >> (t * 4 + nf)) & 1) ? bl : zf;
            }
            #pragma unroll
            for (int mi = 0; mi < 4; ++mi)
                #pragma unroll
                for (int nf = 0; nf < 4; ++nf)
                    acc[mi][nf] = __builtin_amdgcn_mfma_f32_16x16x32_bf16(
                        a[mi], bfr[nf], acc[mi][nf], 0, 0, 0);
        }

        // epilogue
        const int spn = sp0 + wn + l15;
        #pragma unroll
        for (int mi = 0; mi < 4; ++mi) {
            const int km = wm + 16 * mi + 4 * l4;
            #pragma unroll
            for (int reg = 0; reg < 4; ++reg) {
                const int  kk  = km + reg;
                const float ofv = off[kk];
                float* ob = out + (size_t)(b * KOUT + kk) * SP;
                #pragma unroll
                for (int nf = 0; nf < 4; ++nf) {
                    const int sp = spn + 16 * nf;
                    if (sp < SP) ob[sp] = acc[mi][nf][reg] + ofv;
                }
            }
        }
    };

    const int t0 = wk0;
    const int t1 = wk0 + NBLK;          // second tile, if < NTT
    const bool has2 = (t1 < NTT);

    stage(0, t0);                       // cold stage (exposed once per block)
    asm volatile("s_waitcnt vmcnt(0)" ::: "memory");
    __syncthreads();

    if (has2) stage(1, t1);             // prefetch next tile (hidden under compute)
    compute(0, t0);

    if (has2) {
        asm volatile("s_waitcnt vmcnt(0)" ::: "memory");
        __syncthreads();
        compute(1, t1);
    }
}

// ---- fallback: round-1 fp32 direct conv ----
__global__ __launch_bounds__(256)
void conv3x3_kernel(const float* __restrict__ x, const float* __restrict__ w,
                    const float* __restrict__ off, float* __restrict__ out)
{
    const int s  = blockIdx.x * 256 + threadIdx.x;
    const int b  = s / SP;
    const int sp = s - b * SP;
    const int y  = sp / HWD;
    const int xx = sp - y * HWD;
    const int k0 = blockIdx.y * 4;

    const int   xm1 = (xx > 0) ? xx - 1 : 0;
    const int   xp1 = (xx < HWD - 1) ? xx + 1 : HWD - 1;
    const float m0  = (xx > 0) ? 1.f : 0.f;
    const float m2  = (xx < HWD - 1) ? 1.f : 0.f;

    int ro[3]; float msk[3][3];
    #pragma unroll
    for (int ky = 0; ky < 3; ++ky) {
        const int  yy = y + ky - 1;
        const bool ok = (unsigned)yy < (unsigned)HWD;
        const float rm = ok ? 1.f : 0.f;
        ro[ky] = (ok ? yy : 0) * HWD;
        msk[ky][0] = rm * m0; msk[ky][1] = rm; msk[ky][2] = rm * m2;
    }
    float acc[4] = {0.f, 0.f, 0.f, 0.f};
    const float* xb = x + (size_t)b * CIN * SP;
    for (int c = 0; c < CIN; ++c) {
        const float* xc = xb + (size_t)c * SP;
        #pragma unroll
        for (int ky = 0; ky < 3; ++ky) {
            const float* xr = xc + ro[ky];
            const float v0 = xr[xm1] * msk[ky][0];
            const float v1 = xr[xx]  * msk[ky][1];
            const float v2 = xr[xp1] * msk[ky][2];
            const int wi = c * 9 + ky * 3;
            #pragma unroll
            for (int kk = 0; kk < 4; ++kk) {
                const float* wr = w + (size_t)(k0 + kk) * (CIN * 9) + wi;
                acc[kk] = fmaf(v0, wr[0], acc[kk]);
                acc[kk] = fmaf(v1, wr[1], acc[kk]);
                acc[kk] = fmaf(v2, wr[2], acc[kk]);
            }
        }
    }
    #pragma unroll
    for (int kk = 0; kk < 4; ++kk)
        out[(size_t)(b * KOUT + k0 + kk) * SP + sp] = acc[kk] + off[k0 + kk];
}

} // namespace

extern "C" void kernel_launch(void* const* d_in, const int* in_sizes, int n_in,
                              void* d_out, int out_size, void* d_ws, size_t ws_size,
                              hipStream_t stream)
{
    const float* x   = (const float*)d_in[0];
    const float* w   = (const float*)d_in[1];
    const float* off = (const float*)d_in[2];
    float* out = (float*)d_out;

    const size_t wpa_bytes = (size_t)KOUT * KD * 2;          // 147456
    const size_t xt_bytes  = (size_t)BATCH * SP * CIN * 2;   // 12845056

    if (ws_size >= wpa_bytes + xt_bytes) {
        unsigned short* wpA = (unsigned short*)d_ws;
        unsigned short* xT  = (unsigned short*)((char*)d_ws + wpa_bytes);
        prep_kernel<<<TT + WB, 256, 0, stream>>>(x, w, wpA, xT);
        conv_pipe<<<NBLK, dim3(256, 1, 1), 0, stream>>>(xT, wpA, off, out);
    } else {
        dim3 grid((BATCH * SP) / 256, KOUT / 4);
        conv3x3_kernel<<<grid, dim3(256, 1, 1), 0, stream>>>(x, w, off, out);
    }
}

// Round 8
// 42.338 us; speedup vs baseline: 1.3771x; 1.2351x over previous
//
#include <hip/hip_runtime.h>
#include <hip/hip_bf16.h>

namespace {

using frag_t    = __attribute__((ext_vector_type(8))) short;   // 8 bf16 = 16 B
using f32x4     = __attribute__((ext_vector_type(4))) float;   // MFMA acc
using float4_t  = __attribute__((ext_vector_type(4))) float;

constexpr int BATCH = 32;
constexpr int CIN   = 64;
constexpr int HWD   = 56;
constexpr int KOUT  = 128;
constexpr int SP    = HWD * HWD;        // 3136 = 49*64
constexpr int KD    = 9 * CIN;          // 576
constexpr int BN    = 64;               // spatial tile (divides SP exactly)
constexpr int HALO  = 57;
constexpr int NROWS = BN + 2 * HALO;    // 178 valid staged rows
constexpr int NSTA  = 192;              // allocated rows (overflow-safe, 24 KB)
constexpr int NTILES= SP / BN;          // 49
constexpr int NWG   = NTILES * BATCH;   // 1568 = 8 * 196
constexpr int TT    = BATCH * (SP / 64);
constexpr int WB    = (KOUT * KD + 255) / 256;

__device__ inline unsigned short f2bf(float f) {
    __hip_bfloat16 h = __float2bfloat16(f);
    return __builtin_bit_cast(unsigned short, h);
}

// ---- prep: (a) transpose x -> xT[b][sp][c] bf16; (b) repack w -> wpA[kc][kout][32] ----
__global__ __launch_bounds__(256)
void prep_kernel(const float* __restrict__ x, const float* __restrict__ w,
                 unsigned short* __restrict__ wpA, unsigned short* __restrict__ xT)
{
    if (blockIdx.x >= TT) {
        const int idx = (blockIdx.x - TT) * 256 + threadIdx.x;
        if (idx < KOUT * KD) {
            const int kout = idx / KD, kk = idx - kout * KD;
            const int kc = kk >> 5, e = kk & 31;
            const int t = kk >> 6, c = kk & 63;
            const int ky = t / 3, kx = t - ky * 3;
            wpA[(kc * KOUT + kout) * 32 + e] = f2bf(w[((kout * CIN + c) * 3 + ky) * 3 + kx]);
        }
        return;
    }
    __shared__ float ls[64][68];
    const int bb   = blockIdx.x / (SP / 64);
    const int tile = blockIdx.x - bb * (SP / 64);
    const int sp0  = tile * 64;
    const int tid  = threadIdx.x;
    const int cq   = tid >> 4;
    const int spo  = (tid & 15) * 4;
    const float* xb = x + (size_t)bb * CIN * SP;
    #pragma unroll
    for (int j = 0; j < 4; ++j) {
        const int c = cq + 16 * j;
        float4_t v = *(const float4_t*)&xb[(size_t)c * SP + sp0 + spo];
        ls[spo + 0][c] = v.x; ls[spo + 1][c] = v.y;
        ls[spo + 2][c] = v.z; ls[spo + 3][c] = v.w;
    }
    __syncthreads();
    unsigned short* xo = xT + (size_t)(bb * SP + sp0) * 64;
    #pragma unroll
    for (int j = 0; j < 2; ++j) {
        const int s  = tid + 256 * j;
        const int sp = s >> 3, e = s & 7;
        frag_t u;
        #pragma unroll
        for (int q = 0; q < 8; ++q)
            u[q] = (short)f2bf(ls[sp][e * 8 + q]);
        *(frag_t*)&xo[sp * 64 + e * 8] = u;
    }
}

// ---- slim high-occupancy implicit-GEMM conv: 64sp x 128kout per block ----
__global__ __launch_bounds__(256, 5)
void conv_slim(const unsigned short* __restrict__ xT, const unsigned short* __restrict__ wpA,
               const float* __restrict__ off, float* __restrict__ out)
{
    // xs[row][c] bf16; slot [r][z] holds xT[g(r)][z ^ ((r&7)<<3)]
    __shared__ unsigned short xs[NSTA * 64];   // 24 KB

    const int d    = blockIdx.x;
    const int wk   = (d & 7) * (NWG / 8) + (d >> 3);   // bijective XCD swizzle
    const int b    = wk / NTILES;
    const int sp0  = (wk - b * NTILES) * BN;
    const int tid  = threadIdx.x;
    const int lane = tid & 63;
    const int wid  = tid >> 6;

    // ---------- stage 178-row window: pre-swizzled src, direct global->LDS ----------
    {
        const unsigned short* xb = xT + (size_t)b * SP * 64;
        const int lsw = ((lane & 7) * 8) ^ ((lane >> 3) << 3);
        #pragma unroll
        for (int it = 0; it < 6; ++it) {
            const int R0 = it * 32 + wid * 8;       // wave-uniform base row
            const int r  = R0 + (lane >> 3);
            if (r < NROWS) {
                int g = sp0 - HALO + r;
                g = min(max(g, 0), SP - 1);
                __builtin_amdgcn_global_load_lds(
                    (const __attribute__((address_space(1))) unsigned int*)
                        (xb + (size_t)g * 64 + lsw),
                    (__attribute__((address_space(3))) unsigned int*)
                        &xs[R0 * 64 + lane * 8],
                    16, 0, 0);
            }
        }
    }
    asm volatile("s_waitcnt vmcnt(0)" ::: "memory");
    __syncthreads();

    const int wm  = wid * 32;          // 32 kouts per wave
    const int l15 = lane & 15;
    const int l4  = lane >> 4;

    // ---------- per-(tap, nf) validity masks ----------
    unsigned long long mbits = 0ull;
    int yv[4], xv[4];
    #pragma unroll
    for (int nf = 0; nf < 4; ++nf) {
        const int sp = sp0 + nf * 16 + l15;
        yv[nf] = sp / HWD;
        xv[nf] = sp - yv[nf] * HWD;
    }
    #pragma unroll
    for (int t = 0; t < 9; ++t) {
        const int dy = t / 3 - 1, dx = t % 3 - 1;
        #pragma unroll
        for (int nf = 0; nf < 4; ++nf) {
            const bool v = ((unsigned)(yv[nf] + dy) < (unsigned)HWD) &
                           ((unsigned)(xv[nf] + dx) < (unsigned)HWD);
            mbits |= (unsigned long long)(v ? 1 : 0) << (t * 4 + nf);
        }
    }

    const unsigned short* abase = wpA + (size_t)(wm + l15) * 32 + 8 * l4;
    const int cread = 8 * l4;
    const frag_t zf = {0,0,0,0,0,0,0,0};

    f32x4 acc[2][4] = {};              // [mi][nf]

    // ---------- K loop: 18 chunks, no barriers ----------
    #pragma unroll
    for (int kc = 0; kc < 18; ++kc) {
        const int t  = kc >> 1;
        const int c0 = (kc & 1) * 32;
        const int s    = (t / 3 - 1) * HWD + (t % 3 - 1);
        const int row0 = l15 + HALO + s;               // in [0, 129]
        const int sw   = (row0 & 7) << 3;
        frag_t a[2], bfr[4];
        #pragma unroll
        for (int mi = 0; mi < 2; ++mi)
            a[mi] = *(const frag_t*)(abase + (size_t)(kc * KOUT + mi * 16) * 32);
        #pragma unroll
        for (int nf = 0; nf < 4; ++nf) {
            const frag_t bl = *(const frag_t*)&xs[(row0 + 16 * nf) * 64
                                                 + ((c0 + cread) ^ sw)];
            bfr[nf] = ((mbits >> (t * 4 + nf)) & 1) ? bl : zf;
        }
        #pragma unroll
        for (int mi = 0; mi < 2; ++mi)
            #pragma unroll
            for (int nf = 0; nf < 4; ++nf)
                acc[mi][nf] = __builtin_amdgcn_mfma_f32_16x16x32_bf16(
                    a[mi], bfr[nf], acc[mi][nf], 0, 0, 0);
    }

    // ---------- epilogue (tiles divide SP exactly: no guards) ----------
    const int spn = sp0 + l15;
    #pragma unroll
    for (int mi = 0; mi < 2; ++mi) {
        const int km = wm + 16 * mi + 4 * l4;
        #pragma unroll
        for (int reg = 0; reg < 4; ++reg) {
            const int  kk  = km + reg;
            const float ofv = off[kk];
            float* ob = out + (size_t)(b * KOUT + kk) * SP;
            #pragma unroll
            for (int nf = 0; nf < 4; ++nf)
                ob[spn + 16 * nf] = acc[mi][nf][reg] + ofv;
        }
    }
}

// ---- fallback: round-1 fp32 direct conv ----
__global__ __launch_bounds__(256)
void conv3x3_kernel(const float* __restrict__ x, const float* __restrict__ w,
                    const float* __restrict__ off, float* __restrict__ out)
{
    const int s  = blockIdx.x * 256 + threadIdx.x;
    const int b  = s / SP;
    const int sp = s - b * SP;
    const int y  = sp / HWD;
    const int xx = sp - y * HWD;
    const int k0 = blockIdx.y * 4;

    const int   xm1 = (xx > 0) ? xx - 1 : 0;
    const int   xp1 = (xx < HWD - 1) ? xx + 1 : HWD - 1;
    const float m0  = (xx > 0) ? 1.f : 0.f;
    const float m2  = (xx < HWD - 1) ? 1.f : 0.f;

    int ro[3]; float msk[3][3];
    #pragma unroll
    for (int ky = 0; ky < 3; ++ky) {
        const int  yy = y + ky - 1;
        const bool ok = (unsigned)yy < (unsigned)HWD;
        const float rm = ok ? 1.f : 0.f;
        ro[ky] = (ok ? yy : 0) * HWD;
        msk[ky][0] = rm * m0; msk[ky][1] = rm; msk[ky][2] = rm * m2;
    }
    float acc[4] = {0.f, 0.f, 0.f, 0.f};
    const float* xb = x + (size_t)b * CIN * SP;
    for (int c = 0; c < CIN; ++c) {
        const float* xc = xb + (size_t)c * SP;
        #pragma unroll
        for (int ky = 0; ky < 3; ++ky) {
            const float* xr = xc + ro[ky];
            const float v0 = xr[xm1] * msk[ky][0];
            const float v1 = xr[xx]  * msk[ky][1];
            const float v2 = xr[xp1] * msk[ky][2];
            const int wi = c * 9 + ky * 3;
            #pragma unroll
            for (int kk = 0; kk < 4; ++kk) {
                const float* wr = w + (size_t)(k0 + kk) * (CIN * 9) + wi;
                acc[kk] = fmaf(v0, wr[0], acc[kk]);
                acc[kk] = fmaf(v1, wr[1], acc[kk]);
                acc[kk] = fmaf(v2, wr[2], acc[kk]);
            }
        }
    }
    #pragma unroll
    for (int kk = 0; kk < 4; ++kk)
        out[(size_t)(b * KOUT + k0 + kk) * SP + sp] = acc[kk] + off[k0 + kk];
}

} // namespace

extern "C" void kernel_launch(void* const* d_in, const int* in_sizes, int n_in,
                              void* d_out, int out_size, void* d_ws, size_t ws_size,
                              hipStream_t stream)
{
    const float* x   = (const float*)d_in[0];
    const float* w   = (const float*)d_in[1];
    const float* off = (const float*)d_in[2];
    float* out = (float*)d_out;

    const size_t wpa_bytes = (size_t)KOUT * KD * 2;          // 147456
    const size_t xt_bytes  = (size_t)BATCH * SP * CIN * 2;   // 12845056

    if (ws_size >= wpa_bytes + xt_bytes) {
        unsigned short* wpA = (unsigned short*)d_ws;
        unsigned short* xT  = (unsigned short*)((char*)d_ws + wpa_bytes);
        prep_kernel<<<TT + WB, 256, 0, stream>>>(x, w, wpA, xT);
        conv_slim<<<NWG, dim3(256, 1, 1), 0, stream>>>(xT, wpA, off, out);
    } else {
        dim3 grid((BATCH * SP) / 256, KOUT / 4);
        conv3x3_kernel<<<grid, dim3(256, 1, 1), 0, stream>>>(x, w, off, out);
    }
}